// Round 4
// baseline (2793.569 us; speedup 1.0000x reference)
//
#include <hip/hip_runtime.h>
#include <hip/hip_bf16.h>
#include <stdint.h>

// PointNet++ Set Abstraction: FPS -> ball query -> gather -> 3x(conv1x1+BN+ReLU) -> maxpool
// B=8 N=8192 C=64, npoint=1024, r=0.2, nsample=32, MLP 67->64->64->128, BN_EPS=1e-3
//
// Exactness notes:
//  * FPS / ball query distances use __fmul_rn/__fadd_rn (NO fma contraction), order
//    ((dx*dx + dy*dy) + dz*dz), matching the reference.
//  * FPS argmax tie-break = first (lowest) global index, via balanced (val,slot) tree
//    in-thread (strict >) + single u64 key (distbits<<32)|~idx DPP max across lanes/waves.
//  * Ball query keeps first 32 valid indices in ascending order, pads with first hit.
//  * MLP layers run on MFMA (bf16 in, f32 accum). BN stats from f32 accumulators.
//  * max-over-k commutes with relu(bn(.)) (bn slope > 0) -> layer2 stores only the
//    per-(b,s) channel max of z2.

#define INV_CNT (1.0f/262144.0f)

typedef __attribute__((ext_vector_type(8))) short bf16x8;
typedef __attribute__((ext_vector_type(4))) float f32x4;

__device__ __forceinline__ float bf2f(unsigned int v) {
    return __uint_as_float(v << 16);
}
__device__ __forceinline__ unsigned int f2bf(float f) {
    unsigned int u = __float_as_uint(f);
    return (u + 0x7fffu + ((u >> 16) & 1u)) >> 16;   // RNE
}

template<int CTRL>
__device__ __forceinline__ unsigned int dpp_u32(unsigned int x) {
    return (unsigned int)__builtin_amdgcn_update_dpp((int)x, (int)x, CTRL, 0xf, 0xf, false);
}
// DPP ctrl: ROW_SHR:n = 0x110|n, ROW_BCAST15 = 0x142, ROW_BCAST31 = 0x143

// ---------------- FPS: one block per batch, 512 threads, 16 pts/thread ----------------
__global__ __launch_bounds__(512) void fps_kernel(const float* __restrict__ xyz,
                                                  float* __restrict__ nxyz,
                                                  float* __restrict__ out_nxyz) {
    const int b = blockIdx.x;
    const int t = threadIdx.x;
    const int lane = t & 63;
    const int wv = t >> 6;                                   // 0..7
    const float* xb = xyz + (size_t)b * 8192 * 3;
    __shared__ float sx[8192], sy[8192], sz[8192];           // 96 KB coord mirror
    __shared__ unsigned int sdhi[2][8], sdlo[2][8];
    __shared__ int ch[1024];
    float px[16], py[16], pz[16], dist[16];
#pragma unroll
    for (int i = 0; i < 16; ++i) {
        int p = t + i * 512;
        float x = xb[p*3+0], y = xb[p*3+1], z = xb[p*3+2];
        px[i] = x; py[i] = y; pz[i] = z;
        sx[p] = x; sy[p] = y; sz[p] = z;
        dist[i] = 1e10f;
    }
    __syncthreads();
    int far = 0;
    for (int it = 0; it < 1024; ++it) {
        if (t == 0) ch[it] = far;
        float cx = sx[far], cy = sy[far], cz = sz[far];      // uniform LDS broadcast
        float tv[16]; int ti[16];
#pragma unroll
        for (int i = 0; i < 16; ++i) {
            float dx = __fsub_rn(px[i], cx);
            float dy = __fsub_rn(py[i], cy);
            float dz = __fsub_rn(pz[i], cz);
            float d = __fadd_rn(__fadd_rn(__fmul_rn(dx,dx), __fmul_rn(dy,dy)), __fmul_rn(dz,dz));
            float nd = fminf(dist[i], d);
            dist[i] = nd;
            tv[i] = nd; ti[i] = i;
        }
        // balanced (val, slot) tree; strict > keeps lowest slot on ties
#pragma unroll
        for (int s = 8; s >= 1; s >>= 1)
#pragma unroll
            for (int i = 0; i < s; ++i) {
                bool tk = tv[i+s] > tv[i];
                tv[i] = tk ? tv[i+s] : tv[i];
                ti[i] = tk ? ti[i+s] : ti[i];
            }
        unsigned int hi = __float_as_uint(tv[0]);
        unsigned int lo = ~(unsigned int)(t + ti[0]*512);
        // single u64-key wave max via DPP (result lands in lane 63)
#define WSTEP(C) { unsigned int nh = dpp_u32<C>(hi), nl = dpp_u32<C>(lo);          \
                   unsigned long long nk = ((unsigned long long)nh << 32) | nl;     \
                   unsigned long long ck = ((unsigned long long)hi << 32) | lo;     \
                   bool tk = nk > ck; hi = tk ? nh : hi; lo = tk ? nl : lo; }
        WSTEP(0x111) WSTEP(0x112) WSTEP(0x114) WSTEP(0x118) WSTEP(0x142) WSTEP(0x143)
        if (lane == 63) { sdhi[it & 1][wv] = hi; sdlo[it & 1][wv] = lo; }
        __syncthreads();                                     // the only barrier per iter
        unsigned int xh = sdhi[it & 1][lane & 7];
        unsigned int xl = sdlo[it & 1][lane & 7];
#define XSTEP(C) { unsigned int nh = dpp_u32<C>(xh), nl = dpp_u32<C>(xl);          \
                   unsigned long long nk = ((unsigned long long)nh << 32) | nl;     \
                   unsigned long long ck = ((unsigned long long)xh << 32) | xl;     \
                   bool tk = nk > ck; xh = tk ? nh : xh; xl = tk ? nl : xl; }
        XSTEP(0x111) XSTEP(0x112) XSTEP(0x114)
#undef WSTEP
#undef XSTEP
        far = (int)(~(unsigned int)__builtin_amdgcn_readlane((int)xl, 7)) & 8191;
    }
    __syncthreads();
    for (int j = t; j < 1024; j += 512) {
        int ci = ch[j];
        float x = sx[ci], y = sy[ci], z = sz[ci];
        size_t o = (size_t)(b*1024 + j) * 3;
        nxyz[o] = x; nxyz[o+1] = y; nxyz[o+2] = z;
        out_nxyz[o] = x; out_nxyz[o+1] = y; out_nxyz[o+2] = z;
    }
}

// ---------------- Ball query: one wave per center ----------------
__global__ __launch_bounds__(256) void ballquery_kernel(const float* __restrict__ xyz,
                                                        const float* __restrict__ nxyz,
                                                        int* __restrict__ idxbuf) {
    const int wib = threadIdx.x >> 6;
    const int lane = threadIdx.x & 63;
    const int c = blockIdx.x * 4 + wib;        // center id in [0, 8192)
    const int b = c >> 10;
    const float* xb = xyz + (size_t)b * 8192 * 3;
    const float cx = nxyz[c*3+0], cy = nxyz[c*3+1], cz = nxyz[c*3+2];
    const float R2 = 0.04f;
    int count = 0, first = 0;
    int* ob = idxbuf + (size_t)c * 32;
    for (int base = 0; base < 8192; base += 64) {
        int i = base + lane;
        float dx = __fsub_rn(xb[i*3+0], cx);
        float dy = __fsub_rn(xb[i*3+1], cy);
        float dz = __fsub_rn(xb[i*3+2], cz);
        float sq = __fadd_rn(__fadd_rn(__fmul_rn(dx,dx), __fmul_rn(dy,dy)), __fmul_rn(dz,dz));
        bool pass = !(sq > R2);
        unsigned long long mask = __ballot(pass);
        if (count == 0 && mask) first = base + (int)__builtin_ctzll(mask);
        int pos = count + (int)__popcll(mask & ((1ull << lane) - 1ull));
        if (pass && pos < 32) ob[pos] = i;
        count += (int)__popcll(mask);
        if (count >= 32) break;
    }
    if (count < 32 && lane >= count && lane < 32) ob[lane] = first;
}

// ======================= MFMA MLP layers =======================
// Tile: 64 rows x F per block, 4 waves, wave w owns rows [16w,16w+16).
// A-frag: lane l -> row (l&15), k = 8*(l>>4)+[0..7]  (ds_read_b128 from Xb)
// B-frag: lane l -> col (l&15), same k pattern        (ds_read_b128 from Wt, transposed)
// C/D   : lane l -> col (l&15), rows 4*(l>>4)+reg     (HW-verified mapping)

// ---------------- Layer 0: gather(67) @ w0(67x64), K padded to 96, stride 104 ----------------
__global__ __launch_bounds__(256) void layer0_kernel(
        const float* __restrict__ xyz, const float* __restrict__ points,
        const float* __restrict__ nxyz, const int* __restrict__ idxbuf,
        const float* __restrict__ w0, unsigned short* __restrict__ z0,
        float* __restrict__ stats0) {
    __shared__ __attribute__((aligned(16))) unsigned short Xb[64*104];
    __shared__ __attribute__((aligned(16))) unsigned short Wt[64*104];
    __shared__ float ssum[64], ssq[64];
    const int tid = threadIdx.x;
    const int R = blockIdx.x * 64;
    if (tid < 64) { ssum[tid] = 0.f; ssq[tid] = 0.f; }
    // W transpose -> Wt[f][k], bf16, zero-pad k in [67,96)
    for (int i = tid; i < 67*64; i += 256) {
        int k = i >> 6, f = i & 63;
        Wt[f*104 + k] = (unsigned short)f2bf(w0[i]);
    }
    for (int i = tid; i < 29*64; i += 256) {
        int k = 67 + (i % 29), f = i / 29;
        Wt[f*104 + k] = 0;
    }
    // X gather: 4 threads per row
    {
        int r = tid >> 2, q = tid & 3;
        int row = R + r;
        int gi = idxbuf[row];
        int b = row >> 15, s = (row >> 5) & 1023;
        const float* pb = points + (size_t)(b*8192 + gi) * 64;
        int e0 = q*17, e1 = (q == 3) ? 67 : e0 + 17;
        for (int e = e0; e < e1; ++e) {
            float v;
            if (e < 3) v = xyz[(size_t)(b*8192+gi)*3 + e] - nxyz[(size_t)(b*1024+s)*3 + e];
            else       v = pb[e-3];
            Xb[r*104 + e] = (unsigned short)f2bf(v);
        }
    }
    for (int i = tid; i < 29*64; i += 256) {
        int e = 67 + (i % 29), r = i / 29;
        Xb[r*104 + e] = 0;
    }
    __syncthreads();
    const int l = tid & 63, w = tid >> 6;
    const int rsub = l & 15, kq = l >> 4;
    f32x4 acc[4];
#pragma unroll
    for (int cb = 0; cb < 4; ++cb) acc[cb] = (f32x4){0.f, 0.f, 0.f, 0.f};
    const int abase = (w*16 + rsub)*104 + kq*8;
    const int bbase = rsub*104 + kq*8;
#pragma unroll
    for (int ks = 0; ks < 3; ++ks) {
        bf16x8 A = *(const bf16x8*)&Xb[abase + ks*32];
#pragma unroll
        for (int cb = 0; cb < 4; ++cb) {
            bf16x8 Bf = *(const bf16x8*)&Wt[bbase + cb*16*104 + ks*32];
            acc[cb] = __builtin_amdgcn_mfma_f32_16x16x32_bf16(A, Bf, acc[cb], 0, 0, 0);
        }
    }
    unsigned short* zrow = z0 + (size_t)(R + w*16 + kq*4) * 64;
#pragma unroll
    for (int cb = 0; cb < 4; ++cb) {
        int c = cb*16 + rsub;
        float a0 = acc[cb][0], a1 = acc[cb][1], a2 = acc[cb][2], a3 = acc[cb][3];
        atomicAdd(&ssum[c], a0 + a1 + a2 + a3);
        atomicAdd(&ssq[c], a0*a0 + a1*a1 + a2*a2 + a3*a3);
#pragma unroll
        for (int j = 0; j < 4; ++j) zrow[j*64 + c] = (unsigned short)f2bf(acc[cb][j]);
    }
    __syncthreads();
    if (tid < 64) {
        atomicAdd(&stats0[tid], ssum[tid]);
        atomicAdd(&stats0[64+tid], ssq[tid]);
    }
}

// ---------------- Layer 1: relu(bn0(z0)) @ w1(64x64), stride 72 ----------------
__global__ __launch_bounds__(256) void layer1_kernel(
        const unsigned short* __restrict__ z0, const float* __restrict__ stats0,
        const float* __restrict__ gamma0, const float* __restrict__ beta0,
        const float* __restrict__ w1, unsigned short* __restrict__ z1,
        float* __restrict__ stats1) {
    __shared__ __attribute__((aligned(16))) unsigned short Xb[64*72];
    __shared__ __attribute__((aligned(16))) unsigned short Wt[64*72];
    __shared__ float scale[64], shift[64], ssum[64], ssq[64];
    const int tid = threadIdx.x;
    const int R = blockIdx.x * 64;
    if (tid < 64) {
        float m = stats0[tid] * INV_CNT;
        float v = stats0[64+tid] * INV_CNT - m*m;
        float rs = rsqrtf(v + 1e-3f);
        float sc = gamma0[tid] * rs;
        scale[tid] = sc; shift[tid] = beta0[tid] - m*sc;
        ssum[tid] = 0.f; ssq[tid] = 0.f;
    }
    for (int i = tid; i < 64*64; i += 256) {
        int k = i >> 6, f = i & 63;
        Wt[f*72 + k] = (unsigned short)f2bf(w1[i]);
    }
    __syncthreads();                           // scale/shift ready
    const uint4* zg = (const uint4*)(z0 + (size_t)R * 64);
#pragma unroll
    for (int cch = 0; cch < 2; ++cch) {
        int flat8 = tid*2 + cch;               // 8-elem chunk id, 0..511
        uint4 a = zg[flat8];
        int r = flat8 >> 3, e0 = (flat8 & 7) * 8;
        unsigned int uu[4] = {a.x, a.y, a.z, a.w};
        bf16x8 xv;
#pragma unroll
        for (int j = 0; j < 8; ++j) {
            unsigned int ub = (j & 1) ? (uu[j>>1] >> 16) : (uu[j>>1] & 0xffffu);
            float v = bf2f(ub);
            v = fmaxf(v * scale[e0+j] + shift[e0+j], 0.f);
            xv[j] = (short)f2bf(v);
        }
        *(bf16x8*)&Xb[r*72 + e0] = xv;
    }
    __syncthreads();
    const int l = tid & 63, w = tid >> 6;
    const int rsub = l & 15, kq = l >> 4;
    f32x4 acc[4];
#pragma unroll
    for (int cb = 0; cb < 4; ++cb) acc[cb] = (f32x4){0.f, 0.f, 0.f, 0.f};
    const int abase = (w*16 + rsub)*72 + kq*8;
    const int bbase = rsub*72 + kq*8;
#pragma unroll
    for (int ks = 0; ks < 2; ++ks) {
        bf16x8 A = *(const bf16x8*)&Xb[abase + ks*32];
#pragma unroll
        for (int cb = 0; cb < 4; ++cb) {
            bf16x8 Bf = *(const bf16x8*)&Wt[bbase + cb*16*72 + ks*32];
            acc[cb] = __builtin_amdgcn_mfma_f32_16x16x32_bf16(A, Bf, acc[cb], 0, 0, 0);
        }
    }
    unsigned short* zrow = z1 + (size_t)(R + w*16 + kq*4) * 64;
#pragma unroll
    for (int cb = 0; cb < 4; ++cb) {
        int c = cb*16 + rsub;
        float a0 = acc[cb][0], a1 = acc[cb][1], a2 = acc[cb][2], a3 = acc[cb][3];
        atomicAdd(&ssum[c], a0 + a1 + a2 + a3);
        atomicAdd(&ssq[c], a0*a0 + a1*a1 + a2*a2 + a3*a3);
#pragma unroll
        for (int j = 0; j < 4; ++j) zrow[j*64 + c] = (unsigned short)f2bf(acc[cb][j]);
    }
    __syncthreads();
    if (tid < 64) {
        atomicAdd(&stats1[tid], ssum[tid]);
        atomicAdd(&stats1[64+tid], ssq[tid]);
    }
}

// ------- Layer 2: relu(bn1(z1)) @ w2(64x128); per-(b,s) channel max + stats -------
__global__ __launch_bounds__(256) void layer2_kernel(
        const unsigned short* __restrict__ z1, const float* __restrict__ stats1,
        const float* __restrict__ gamma1, const float* __restrict__ beta1,
        const float* __restrict__ w2, float* __restrict__ maxz2,
        float* __restrict__ stats2) {
    __shared__ __attribute__((aligned(16))) unsigned short Xb[64*72];
    __shared__ __attribute__((aligned(16))) unsigned short Wt[128*72];
    __shared__ float scale[64], shift[64];
    __shared__ float ssum[128], ssq[128];
    __shared__ float gmx[2][8][128];
    const int tid = threadIdx.x;
    const int R = blockIdx.x * 64;
    if (tid < 64) {
        float m = stats1[tid] * INV_CNT;
        float v = stats1[64+tid] * INV_CNT - m*m;
        float rs = rsqrtf(v + 1e-3f);
        float sc = gamma1[tid] * rs;
        scale[tid] = sc; shift[tid] = beta1[tid] - m*sc;
    }
    if (tid < 128) { ssum[tid] = 0.f; ssq[tid] = 0.f; }
    for (int i = tid; i < 64*128; i += 256) {
        int k = i >> 7, f = i & 127;
        Wt[f*72 + k] = (unsigned short)f2bf(w2[i]);
    }
    __syncthreads();
    const uint4* zg = (const uint4*)(z1 + (size_t)R * 64);
#pragma unroll
    for (int cch = 0; cch < 2; ++cch) {
        int flat8 = tid*2 + cch;
        uint4 a = zg[flat8];
        int r = flat8 >> 3, e0 = (flat8 & 7) * 8;
        unsigned int uu[4] = {a.x, a.y, a.z, a.w};
        bf16x8 xv;
#pragma unroll
        for (int j = 0; j < 8; ++j) {
            unsigned int ub = (j & 1) ? (uu[j>>1] >> 16) : (uu[j>>1] & 0xffffu);
            float v = bf2f(ub);
            v = fmaxf(v * scale[e0+j] + shift[e0+j], 0.f);
            xv[j] = (short)f2bf(v);
        }
        *(bf16x8*)&Xb[r*72 + e0] = xv;
    }
    __syncthreads();
    const int l = tid & 63, w = tid >> 6;
    const int rsub = l & 15, kq = l >> 4;
    f32x4 acc[8];
#pragma unroll
    for (int cb = 0; cb < 8; ++cb) acc[cb] = (f32x4){0.f, 0.f, 0.f, 0.f};
    const int abase = (w*16 + rsub)*72 + kq*8;
    const int bbase = rsub*72 + kq*8;
#pragma unroll
    for (int ks = 0; ks < 2; ++ks) {
        bf16x8 A = *(const bf16x8*)&Xb[abase + ks*32];
#pragma unroll
        for (int cb = 0; cb < 8; ++cb) {
            bf16x8 Bf = *(const bf16x8*)&Wt[bbase + cb*16*72 + ks*32];
            acc[cb] = __builtin_amdgcn_mfma_f32_16x16x32_bf16(A, Bf, acc[cb], 0, 0, 0);
        }
    }
    const int g = w >> 1;                       // 32-row group within block
    const int contrib = (w & 1) * 4 + kq;       // 0..7
#pragma unroll
    for (int cb = 0; cb < 8; ++cb) {
        int c = cb*16 + rsub;
        float a0 = acc[cb][0], a1 = acc[cb][1], a2 = acc[cb][2], a3 = acc[cb][3];
        atomicAdd(&ssum[c], a0 + a1 + a2 + a3);
        atomicAdd(&ssq[c], a0*a0 + a1*a1 + a2*a2 + a3*a3);
        gmx[g][contrib][c] = fmaxf(fmaxf(a0, a1), fmaxf(a2, a3));
    }
    __syncthreads();
    {
        int gg = tid >> 7, c = tid & 127;
        float m = gmx[gg][0][c];
#pragma unroll
        for (int i = 1; i < 8; ++i) m = fmaxf(m, gmx[gg][i][c]);
        maxz2[(size_t)(blockIdx.x*2 + gg) * 128 + c] = m;
    }
    if (tid < 128) {
        atomicAdd(&stats2[tid], ssum[tid]);
        atomicAdd(&stats2[128+tid], ssq[tid]);
    }
}

// ---------------- Final: out = relu(bn2(maxz2)) ----------------
__global__ __launch_bounds__(256) void final_kernel(
        const float* __restrict__ maxz2, const float* __restrict__ stats2,
        const float* __restrict__ gamma2, const float* __restrict__ beta2,
        float* __restrict__ out) {
    const int i = blockIdx.x * 256 + threadIdx.x;    // over 8*1024*128
    const int f = i & 127;
    float m = stats2[f] * INV_CNT;
    float v = stats2[128+f] * INV_CNT - m*m;
    float rs = rsqrtf(v + 1e-3f);
    out[24576 + i] = fmaxf(gamma2[f]*((maxz2[i]-m)*rs) + beta2[f], 0.f);
}

extern "C" void kernel_launch(void* const* d_in, const int* in_sizes, int n_in,
                              void* d_out, int out_size, void* d_ws, size_t ws_size,
                              hipStream_t stream) {
    const float* xyz    = (const float*)d_in[0];
    const float* points = (const float*)d_in[1];
    const float* w0     = (const float*)d_in[2];
    const float* g0     = (const float*)d_in[3];
    const float* b0     = (const float*)d_in[4];
    const float* w1     = (const float*)d_in[5];
    const float* g1     = (const float*)d_in[6];
    const float* b1     = (const float*)d_in[7];
    const float* w2     = (const float*)d_in[8];
    const float* g2     = (const float*)d_in[9];
    const float* b2     = (const float*)d_in[10];
    float* out = (float*)d_out;
    char* ws = (char*)d_ws;

    // workspace layout (bytes), all 256-aligned:
    float* nxyz            = (float*)(ws + 0);          // 24576 f32
    int*   idxbuf          = (int*)  (ws + 98304);      // 262144 i32
    float* stats           = (float*)(ws + 1146880);    // 512 f32 (s0:128, s1:128, s2:256)
    unsigned short* z0     = (unsigned short*)(ws + 1148928);   // 32 MB bf16
    unsigned short* z1     = (unsigned short*)(ws + 34703360);  // 32 MB bf16
    float* maxz2           = (float*)(ws + 68257792);   // 4 MB f32

    hipMemsetAsync(stats, 0, 512 * sizeof(float), stream);
    fps_kernel<<<8, 512, 0, stream>>>(xyz, nxyz, out);
    ballquery_kernel<<<2048, 256, 0, stream>>>(xyz, nxyz, idxbuf);
    layer0_kernel<<<4096, 256, 0, stream>>>(xyz, points, nxyz, idxbuf, w0, z0, stats);
    layer1_kernel<<<4096, 256, 0, stream>>>(z0, stats, g0, b0, w1, z1, stats + 128);
    layer2_kernel<<<4096, 256, 0, stream>>>(z1, stats + 128, g1, b1, w2, maxz2, stats + 256);
    final_kernel<<<4096, 256, 0, stream>>>(maxz2, stats + 256, g2, b2, out);
}

// Round 5
// 1336.284 us; speedup vs baseline: 2.0906x; 2.0906x over previous
//
#include <hip/hip_runtime.h>
#include <hip/hip_bf16.h>
#include <stdint.h>

// PointNet++ Set Abstraction: FPS -> ball query -> gather -> 3x(conv1x1+BN+ReLU) -> maxpool
// B=8 N=8192 C=64, npoint=1024, r=0.2, nsample=32, MLP 67->64->64->128, BN_EPS=1e-3
//
// Exactness notes:
//  * FPS / ball query distances: exact per-op IEEE f32, order ((dx*dx+dy*dy)+dz*dz).
//    fps uses "#pragma clang fp contract(off)" (allows v_pk_* packed f32, forbids fma
//    contraction -> bit-identical to __f*_rn scalar); ballquery keeps _rn intrinsics.
//  * FPS argmax tie-break = first (lowest) global index: exact wave value-max (DPP),
//    then min-global-index among dist==wavemax, then cross-wave u64 key
//    (distbits<<32)|~idx maximized. Identical winner to reference argmax.
//  * Ball query keeps first 32 valid indices in ascending order, pads with first hit.
//  * MLP layers run on MFMA (bf16 in, f32 accum). BN stats from f32 accumulators.
//  * max-over-k commutes with relu(bn(.)) (bn slope > 0) -> layer2 stores only the
//    per-(b,s) channel max of z2.

#define INV_CNT (1.0f/262144.0f)

typedef __attribute__((ext_vector_type(8))) short bf16x8;
typedef __attribute__((ext_vector_type(4))) float f32x4;

__device__ __forceinline__ float bf2f(unsigned int v) {
    return __uint_as_float(v << 16);
}
__device__ __forceinline__ unsigned int f2bf(float f) {
    unsigned int u = __float_as_uint(f);
    return (u + 0x7fffu + ((u >> 16) & 1u)) >> 16;   // RNE
}

template<int CTRL>
__device__ __forceinline__ unsigned int dpp_u32(unsigned int x) {
    return (unsigned int)__builtin_amdgcn_update_dpp((int)x, (int)x, CTRL, 0xf, 0xf, false);
}
template<int CTRL>
__device__ __forceinline__ float dpp_f32(float x) {
    return __uint_as_float(dpp_u32<CTRL>(__float_as_uint(x)));
}
// DPP ctrl: ROW_SHR:n = 0x110|n, ROW_BCAST15 = 0x142, ROW_BCAST31 = 0x143

__device__ __forceinline__ float2 fmin2(float2 a, float2 b) {
    return make_float2(fminf(a.x, b.x), fminf(a.y, b.y));
}
__device__ __forceinline__ float2 fmax2(float2 a, float2 b) {
    return make_float2(fmaxf(a.x, b.x), fmaxf(a.y, b.y));
}

// ---------------- FPS: one block per batch, 512 threads, 16 pts/thread ----------------
__global__ __launch_bounds__(512) void fps_kernel(const float* __restrict__ xyz,
                                                  float* __restrict__ nxyz,
                                                  float* __restrict__ out_nxyz) {
#pragma clang fp contract(off)
    const int b = blockIdx.x;
    const int t = threadIdx.x;
    const int lane = t & 63;
    const int wv = t >> 6;                                   // 0..7
    const float* xb = xyz + (size_t)b * 8192 * 3;
    __shared__ float sx[8192], sy[8192], sz[8192];           // 96 KB coord mirror
    __shared__ unsigned long long sdk[2][8];                 // per-wave (distbits<<32)|~idx
    __shared__ int ch[1024];
    float2 px[8], py[8], pz[8], dist[8];                     // pair j: pts t+2j*512, t+(2j+1)*512
#pragma unroll
    for (int j = 0; j < 8; ++j) {
        int p0 = t + (2*j)*512, p1 = t + (2*j+1)*512;
        float x0 = xb[p0*3+0], y0 = xb[p0*3+1], z0 = xb[p0*3+2];
        float x1 = xb[p1*3+0], y1 = xb[p1*3+1], z1 = xb[p1*3+2];
        px[j] = make_float2(x0, x1); py[j] = make_float2(y0, y1); pz[j] = make_float2(z0, z1);
        sx[p0] = x0; sy[p0] = y0; sz[p0] = z0;
        sx[p1] = x1; sy[p1] = y1; sz[p1] = z1;
        dist[j] = make_float2(1e10f, 1e10f);
    }
    __syncthreads();
    int far = 0;
    for (int it = 0; it < 1024; ++it) {
        if (t == 0) ch[it] = far;
        float cx = sx[far], cy = sy[far], cz = sz[far];      // uniform LDS broadcast
        float2 c2x = make_float2(cx, cx), c2y = make_float2(cy, cy), c2z = make_float2(cz, cz);
        float2 mx2 = make_float2(-1.f, -1.f);
#pragma unroll
        for (int j = 0; j < 8; ++j) {
            float2 dx = px[j] - c2x;
            float2 dy = py[j] - c2y;
            float2 dz = pz[j] - c2z;
            float2 d = (dx*dx + dy*dy) + dz*dz;              // contract(off): exact per-op
            float2 nd = fmin2(dist[j], d);
            dist[j] = nd;
            mx2 = fmax2(mx2, nd);
        }
        float v = fmaxf(mx2.x, mx2.y);
        // wave64 value max via DPP (result accumulates into lane 63)
        v = fmaxf(v, dpp_f32<0x111>(v));
        v = fmaxf(v, dpp_f32<0x112>(v));
        v = fmaxf(v, dpp_f32<0x114>(v));
        v = fmaxf(v, dpp_f32<0x118>(v));
        v = fmaxf(v, dpp_f32<0x142>(v));
        v = fmaxf(v, dpp_f32<0x143>(v));
        float wm = __uint_as_float((unsigned int)__builtin_amdgcn_readlane((int)__float_as_uint(v), 63));
        // lowest slot i (0..15) with dist == wm; sentinel 64
        unsigned int ci = 64u;
#pragma unroll
        for (int j = 7; j >= 0; --j) {
            if (dist[j].y == wm) ci = (unsigned int)(2*j+1);
            if (dist[j].x == wm) ci = (unsigned int)(2*j);
        }
        unsigned int idx = (ci == 64u) ? 0xffffffffu : (unsigned int)t + (ci << 9);
        // wave min of idx via DPP (accumulates into lane 63)
        { unsigned int n;
          n = dpp_u32<0x111>(idx); idx = (n < idx) ? n : idx;
          n = dpp_u32<0x112>(idx); idx = (n < idx) ? n : idx;
          n = dpp_u32<0x114>(idx); idx = (n < idx) ? n : idx;
          n = dpp_u32<0x118>(idx); idx = (n < idx) ? n : idx;
          n = dpp_u32<0x142>(idx); idx = (n < idx) ? n : idx;
          n = dpp_u32<0x143>(idx); idx = (n < idx) ? n : idx; }
        if (lane == 63)
            sdk[it & 1][wv] = ((unsigned long long)__float_as_uint(v) << 32)
                            | (unsigned long long)(~idx);
        __syncthreads();                                     // the only barrier per iter
        unsigned long long k = sdk[it & 1][lane & 7];
        unsigned int xh = (unsigned int)(k >> 32), xl = (unsigned int)k;
#define XSTEP(C) { unsigned int nh = dpp_u32<C>(xh), nl = dpp_u32<C>(xl);          \
                   unsigned long long nk = ((unsigned long long)nh << 32) | nl;     \
                   unsigned long long ck = ((unsigned long long)xh << 32) | xl;     \
                   bool tk = nk > ck; xh = tk ? nh : xh; xl = tk ? nl : xl; }
        XSTEP(0x111) XSTEP(0x112) XSTEP(0x114)
#undef XSTEP
        far = (int)(~(unsigned int)__builtin_amdgcn_readlane((int)xl, 7)) & 8191;
    }
    __syncthreads();
    for (int j = t; j < 1024; j += 512) {
        int ci = ch[j];
        float x = sx[ci], y = sy[ci], z = sz[ci];
        size_t o = (size_t)(b*1024 + j) * 3;
        nxyz[o] = x; nxyz[o+1] = y; nxyz[o+2] = z;
        out_nxyz[o] = x; out_nxyz[o+1] = y; out_nxyz[o+2] = z;
    }
}

// ---------------- Ball query: one wave per center ----------------
__global__ __launch_bounds__(256) void ballquery_kernel(const float* __restrict__ xyz,
                                                        const float* __restrict__ nxyz,
                                                        int* __restrict__ idxbuf) {
    const int wib = threadIdx.x >> 6;
    const int lane = threadIdx.x & 63;
    const int c = blockIdx.x * 4 + wib;        // center id in [0, 8192)
    const int b = c >> 10;
    const float* xb = xyz + (size_t)b * 8192 * 3;
    const float cx = nxyz[c*3+0], cy = nxyz[c*3+1], cz = nxyz[c*3+2];
    const float R2 = 0.04f;
    int count = 0, first = 0;
    int* ob = idxbuf + (size_t)c * 32;
    for (int base = 0; base < 8192; base += 64) {
        int i = base + lane;
        float dx = __fsub_rn(xb[i*3+0], cx);
        float dy = __fsub_rn(xb[i*3+1], cy);
        float dz = __fsub_rn(xb[i*3+2], cz);
        float sq = __fadd_rn(__fadd_rn(__fmul_rn(dx,dx), __fmul_rn(dy,dy)), __fmul_rn(dz,dz));
        bool pass = !(sq > R2);
        unsigned long long mask = __ballot(pass);
        if (count == 0 && mask) first = base + (int)__builtin_ctzll(mask);
        int pos = count + (int)__popcll(mask & ((1ull << lane) - 1ull));
        if (pass && pos < 32) ob[pos] = i;
        count += (int)__popcll(mask);
        if (count >= 32) break;
    }
    if (count < 32 && lane >= count && lane < 32) ob[lane] = first;
}

// ======================= MFMA MLP layers =======================
// Tile: 64 rows x F per block, 4 waves, wave w owns rows [16w,16w+16).
// A-frag: lane l -> row (l&15), k = 8*(l>>4)+[0..7]  (ds_read_b128 from Xb)
// B-frag: lane l -> col (l&15), same k pattern        (ds_read_b128 from Wt, transposed)
// C/D   : lane l -> col (l&15), rows 4*(l>>4)+reg     (HW-verified mapping)

// ---------------- Layer 0: gather(67) @ w0(67x64), K padded to 96, stride 104 ----------------
__global__ __launch_bounds__(256) void layer0_kernel(
        const float* __restrict__ xyz, const float* __restrict__ points,
        const float* __restrict__ nxyz, const int* __restrict__ idxbuf,
        const float* __restrict__ w0, unsigned short* __restrict__ z0,
        float* __restrict__ stats0) {
    __shared__ __attribute__((aligned(16))) unsigned short Xb[64*104];
    __shared__ __attribute__((aligned(16))) unsigned short Wt[64*104];
    __shared__ float ssum[64], ssq[64];
    const int tid = threadIdx.x;
    const int R = blockIdx.x * 64;
    if (tid < 64) { ssum[tid] = 0.f; ssq[tid] = 0.f; }
    // W transpose -> Wt[f][k], bf16, zero-pad k in [67,96)
    for (int i = tid; i < 67*64; i += 256) {
        int k = i >> 6, f = i & 63;
        Wt[f*104 + k] = (unsigned short)f2bf(w0[i]);
    }
    for (int i = tid; i < 29*64; i += 256) {
        int k = 67 + (i % 29), f = i / 29;
        Wt[f*104 + k] = 0;
    }
    // X gather: 4 threads per row
    {
        int r = tid >> 2, q = tid & 3;
        int row = R + r;
        int gi = idxbuf[row];
        int b = row >> 15, s = (row >> 5) & 1023;
        const float* pb = points + (size_t)(b*8192 + gi) * 64;
        int e0 = q*17, e1 = (q == 3) ? 67 : e0 + 17;
        for (int e = e0; e < e1; ++e) {
            float v;
            if (e < 3) v = xyz[(size_t)(b*8192+gi)*3 + e] - nxyz[(size_t)(b*1024+s)*3 + e];
            else       v = pb[e-3];
            Xb[r*104 + e] = (unsigned short)f2bf(v);
        }
    }
    for (int i = tid; i < 29*64; i += 256) {
        int e = 67 + (i % 29), r = i / 29;
        Xb[r*104 + e] = 0;
    }
    __syncthreads();
    const int l = tid & 63, w = tid >> 6;
    const int rsub = l & 15, kq = l >> 4;
    f32x4 acc[4];
#pragma unroll
    for (int cb = 0; cb < 4; ++cb) acc[cb] = (f32x4){0.f, 0.f, 0.f, 0.f};
    const int abase = (w*16 + rsub)*104 + kq*8;
    const int bbase = rsub*104 + kq*8;
#pragma unroll
    for (int ks = 0; ks < 3; ++ks) {
        bf16x8 A = *(const bf16x8*)&Xb[abase + ks*32];
#pragma unroll
        for (int cb = 0; cb < 4; ++cb) {
            bf16x8 Bf = *(const bf16x8*)&Wt[bbase + cb*16*104 + ks*32];
            acc[cb] = __builtin_amdgcn_mfma_f32_16x16x32_bf16(A, Bf, acc[cb], 0, 0, 0);
        }
    }
    unsigned short* zrow = z0 + (size_t)(R + w*16 + kq*4) * 64;
#pragma unroll
    for (int cb = 0; cb < 4; ++cb) {
        int c = cb*16 + rsub;
        float a0 = acc[cb][0], a1 = acc[cb][1], a2 = acc[cb][2], a3 = acc[cb][3];
        atomicAdd(&ssum[c], a0 + a1 + a2 + a3);
        atomicAdd(&ssq[c], a0*a0 + a1*a1 + a2*a2 + a3*a3);
#pragma unroll
        for (int j = 0; j < 4; ++j) zrow[j*64 + c] = (unsigned short)f2bf(acc[cb][j]);
    }
    __syncthreads();
    if (tid < 64) {
        atomicAdd(&stats0[tid], ssum[tid]);
        atomicAdd(&stats0[64+tid], ssq[tid]);
    }
}

// ---------------- Layer 1: relu(bn0(z0)) @ w1(64x64), stride 72 ----------------
__global__ __launch_bounds__(256) void layer1_kernel(
        const unsigned short* __restrict__ z0, const float* __restrict__ stats0,
        const float* __restrict__ gamma0, const float* __restrict__ beta0,
        const float* __restrict__ w1, unsigned short* __restrict__ z1,
        float* __restrict__ stats1) {
    __shared__ __attribute__((aligned(16))) unsigned short Xb[64*72];
    __shared__ __attribute__((aligned(16))) unsigned short Wt[64*72];
    __shared__ float scale[64], shift[64], ssum[64], ssq[64];
    const int tid = threadIdx.x;
    const int R = blockIdx.x * 64;
    if (tid < 64) {
        float m = stats0[tid] * INV_CNT;
        float v = stats0[64+tid] * INV_CNT - m*m;
        float rs = rsqrtf(v + 1e-3f);
        float sc = gamma0[tid] * rs;
        scale[tid] = sc; shift[tid] = beta0[tid] - m*sc;
        ssum[tid] = 0.f; ssq[tid] = 0.f;
    }
    for (int i = tid; i < 64*64; i += 256) {
        int k = i >> 6, f = i & 63;
        Wt[f*72 + k] = (unsigned short)f2bf(w1[i]);
    }
    __syncthreads();                           // scale/shift ready
    const uint4* zg = (const uint4*)(z0 + (size_t)R * 64);
#pragma unroll
    for (int cch = 0; cch < 2; ++cch) {
        int flat8 = tid*2 + cch;               // 8-elem chunk id, 0..511
        uint4 a = zg[flat8];
        int r = flat8 >> 3, e0 = (flat8 & 7) * 8;
        unsigned int uu[4] = {a.x, a.y, a.z, a.w};
        bf16x8 xv;
#pragma unroll
        for (int j = 0; j < 8; ++j) {
            unsigned int ub = (j & 1) ? (uu[j>>1] >> 16) : (uu[j>>1] & 0xffffu);
            float v = bf2f(ub);
            v = fmaxf(v * scale[e0+j] + shift[e0+j], 0.f);
            xv[j] = (short)f2bf(v);
        }
        *(bf16x8*)&Xb[r*72 + e0] = xv;
    }
    __syncthreads();
    const int l = tid & 63, w = tid >> 6;
    const int rsub = l & 15, kq = l >> 4;
    f32x4 acc[4];
#pragma unroll
    for (int cb = 0; cb < 4; ++cb) acc[cb] = (f32x4){0.f, 0.f, 0.f, 0.f};
    const int abase = (w*16 + rsub)*72 + kq*8;
    const int bbase = rsub*72 + kq*8;
#pragma unroll
    for (int ks = 0; ks < 2; ++ks) {
        bf16x8 A = *(const bf16x8*)&Xb[abase + ks*32];
#pragma unroll
        for (int cb = 0; cb < 4; ++cb) {
            bf16x8 Bf = *(const bf16x8*)&Wt[bbase + cb*16*72 + ks*32];
            acc[cb] = __builtin_amdgcn_mfma_f32_16x16x32_bf16(A, Bf, acc[cb], 0, 0, 0);
        }
    }
    unsigned short* zrow = z1 + (size_t)(R + w*16 + kq*4) * 64;
#pragma unroll
    for (int cb = 0; cb < 4; ++cb) {
        int c = cb*16 + rsub;
        float a0 = acc[cb][0], a1 = acc[cb][1], a2 = acc[cb][2], a3 = acc[cb][3];
        atomicAdd(&ssum[c], a0 + a1 + a2 + a3);
        atomicAdd(&ssq[c], a0*a0 + a1*a1 + a2*a2 + a3*a3);
#pragma unroll
        for (int j = 0; j < 4; ++j) zrow[j*64 + c] = (unsigned short)f2bf(acc[cb][j]);
    }
    __syncthreads();
    if (tid < 64) {
        atomicAdd(&stats1[tid], ssum[tid]);
        atomicAdd(&stats1[64+tid], ssq[tid]);
    }
}

// ------- Layer 2: relu(bn1(z1)) @ w2(64x128); per-(b,s) channel max + stats -------
__global__ __launch_bounds__(256) void layer2_kernel(
        const unsigned short* __restrict__ z1, const float* __restrict__ stats1,
        const float* __restrict__ gamma1, const float* __restrict__ beta1,
        const float* __restrict__ w2, float* __restrict__ maxz2,
        float* __restrict__ stats2) {
    __shared__ __attribute__((aligned(16))) unsigned short Xb[64*72];
    __shared__ __attribute__((aligned(16))) unsigned short Wt[128*72];
    __shared__ float scale[64], shift[64];
    __shared__ float ssum[128], ssq[128];
    __shared__ float gmx[2][8][128];
    const int tid = threadIdx.x;
    const int R = blockIdx.x * 64;
    if (tid < 64) {
        float m = stats1[tid] * INV_CNT;
        float v = stats1[64+tid] * INV_CNT - m*m;
        float rs = rsqrtf(v + 1e-3f);
        float sc = gamma1[tid] * rs;
        scale[tid] = sc; shift[tid] = beta1[tid] - m*sc;
    }
    if (tid < 128) { ssum[tid] = 0.f; ssq[tid] = 0.f; }
    for (int i = tid; i < 64*128; i += 256) {
        int k = i >> 7, f = i & 127;
        Wt[f*72 + k] = (unsigned short)f2bf(w2[i]);
    }
    __syncthreads();
    const uint4* zg = (const uint4*)(z1 + (size_t)R * 64);
#pragma unroll
    for (int cch = 0; cch < 2; ++cch) {
        int flat8 = tid*2 + cch;
        uint4 a = zg[flat8];
        int r = flat8 >> 3, e0 = (flat8 & 7) * 8;
        unsigned int uu[4] = {a.x, a.y, a.z, a.w};
        bf16x8 xv;
#pragma unroll
        for (int j = 0; j < 8; ++j) {
            unsigned int ub = (j & 1) ? (uu[j>>1] >> 16) : (uu[j>>1] & 0xffffu);
            float v = bf2f(ub);
            v = fmaxf(v * scale[e0+j] + shift[e0+j], 0.f);
            xv[j] = (short)f2bf(v);
        }
        *(bf16x8*)&Xb[r*72 + e0] = xv;
    }
    __syncthreads();
    const int l = tid & 63, w = tid >> 6;
    const int rsub = l & 15, kq = l >> 4;
    f32x4 acc[8];
#pragma unroll
    for (int cb = 0; cb < 8; ++cb) acc[cb] = (f32x4){0.f, 0.f, 0.f, 0.f};
    const int abase = (w*16 + rsub)*72 + kq*8;
    const int bbase = rsub*72 + kq*8;
#pragma unroll
    for (int ks = 0; ks < 2; ++ks) {
        bf16x8 A = *(const bf16x8*)&Xb[abase + ks*32];
#pragma unroll
        for (int cb = 0; cb < 8; ++cb) {
            bf16x8 Bf = *(const bf16x8*)&Wt[bbase + cb*16*72 + ks*32];
            acc[cb] = __builtin_amdgcn_mfma_f32_16x16x32_bf16(A, Bf, acc[cb], 0, 0, 0);
        }
    }
    const int g = w >> 1;                       // 32-row group within block
    const int contrib = (w & 1) * 4 + kq;       // 0..7
#pragma unroll
    for (int cb = 0; cb < 8; ++cb) {
        int c = cb*16 + rsub;
        float a0 = acc[cb][0], a1 = acc[cb][1], a2 = acc[cb][2], a3 = acc[cb][3];
        atomicAdd(&ssum[c], a0 + a1 + a2 + a3);
        atomicAdd(&ssq[c], a0*a0 + a1*a1 + a2*a2 + a3*a3);
        gmx[g][contrib][c] = fmaxf(fmaxf(a0, a1), fmaxf(a2, a3));
    }
    __syncthreads();
    {
        int gg = tid >> 7, c = tid & 127;
        float m = gmx[gg][0][c];
#pragma unroll
        for (int i = 1; i < 8; ++i) m = fmaxf(m, gmx[gg][i][c]);
        maxz2[(size_t)(blockIdx.x*2 + gg) * 128 + c] = m;
    }
    if (tid < 128) {
        atomicAdd(&stats2[tid], ssum[tid]);
        atomicAdd(&stats2[128+tid], ssq[tid]);
    }
}

// ---------------- Final: out = relu(bn2(maxz2)) ----------------
__global__ __launch_bounds__(256) void final_kernel(
        const float* __restrict__ maxz2, const float* __restrict__ stats2,
        const float* __restrict__ gamma2, const float* __restrict__ beta2,
        float* __restrict__ out) {
    const int i = blockIdx.x * 256 + threadIdx.x;    // over 8*1024*128
    const int f = i & 127;
    float m = stats2[f] * INV_CNT;
    float v = stats2[128+f] * INV_CNT - m*m;
    float rs = rsqrtf(v + 1e-3f);
    out[24576 + i] = fmaxf(gamma2[f]*((maxz2[i]-m)*rs) + beta2[f], 0.f);
}

extern "C" void kernel_launch(void* const* d_in, const int* in_sizes, int n_in,
                              void* d_out, int out_size, void* d_ws, size_t ws_size,
                              hipStream_t stream) {
    const float* xyz    = (const float*)d_in[0];
    const float* points = (const float*)d_in[1];
    const float* w0     = (const float*)d_in[2];
    const float* g0     = (const float*)d_in[3];
    const float* b0     = (const float*)d_in[4];
    const float* w1     = (const float*)d_in[5];
    const float* g1     = (const float*)d_in[6];
    const float* b1     = (const float*)d_in[7];
    const float* w2     = (const float*)d_in[8];
    const float* g2     = (const float*)d_in[9];
    const float* b2     = (const float*)d_in[10];
    float* out = (float*)d_out;
    char* ws = (char*)d_ws;

    // workspace layout (bytes), all 256-aligned:
    float* nxyz            = (float*)(ws + 0);          // 24576 f32
    int*   idxbuf          = (int*)  (ws + 98304);      // 262144 i32
    float* stats           = (float*)(ws + 1146880);    // 512 f32 (s0:128, s1:128, s2:256)
    unsigned short* z0     = (unsigned short*)(ws + 1148928);   // 32 MB bf16
    unsigned short* z1     = (unsigned short*)(ws + 34703360);  // 32 MB bf16
    float* maxz2           = (float*)(ws + 68257792);   // 4 MB f32

    hipMemsetAsync(stats, 0, 512 * sizeof(float), stream);
    fps_kernel<<<8, 512, 0, stream>>>(xyz, nxyz, out);
    ballquery_kernel<<<2048, 256, 0, stream>>>(xyz, nxyz, idxbuf);
    layer0_kernel<<<4096, 256, 0, stream>>>(xyz, points, nxyz, idxbuf, w0, z0, stats);
    layer1_kernel<<<4096, 256, 0, stream>>>(z0, stats, g0, b0, w1, z1, stats + 128);
    layer2_kernel<<<4096, 256, 0, stream>>>(z1, stats + 128, g1, b1, w2, maxz2, stats + 256);
    final_kernel<<<4096, 256, 0, stream>>>(maxz2, stats + 256, g2, b2, out);
}